// Round 3
// baseline (416.757 us; speedup 1.0000x reference)
//
#include <hip/hip_runtime.h>
#include <hip/hip_bf16.h>
#include <stdint.h>

#define TOKENS 8192
#define IN_F   4096
#define OUT_F  4096
#define RANK   512

typedef __attribute__((ext_vector_type(8))) __bf16 bf16x8;
typedef __attribute__((ext_vector_type(4))) float f32x4;
typedef __attribute__((ext_vector_type(16))) float f32x16;
typedef __attribute__((ext_vector_type(4))) short short4v;

static __device__ __forceinline__ unsigned short f2bf(float f) {
  union { float f; unsigned u; } v; v.f = f;
  return (unsigned short)((v.u + 0x7FFFu + ((v.u >> 16) & 1u)) >> 16);
}

static __device__ __forceinline__ void gload_lds16(const void* g, void* l) {
  __builtin_amdgcn_global_load_lds(
      (const __attribute__((address_space(1))) unsigned*)g,
      (__attribute__((address_space(3))) unsigned*)l, 16, 0, 0);
}

// ---------------------------------------------------------------------------
// Kernel 0: x f32 -> bf16
// ---------------------------------------------------------------------------
__global__ __launch_bounds__(256) void convert_x(const float* __restrict__ x,
                                                 unsigned short* __restrict__ xb,
                                                 int n4) {
  int idx = blockIdx.x * blockDim.x + threadIdx.x;
  int stride = gridDim.x * blockDim.x;
  for (int i = idx; i < n4; i += stride) {
    f32x4 v = ((const f32x4*)x)[i];
    short4v o;
    o.x = (short)f2bf(v.x);
    o.y = (short)f2bf(v.y);
    o.z = (short)f2bf(v.z);
    o.w = (short)f2bf(v.w);
    ((short4v*)xb)[i] = o;
  }
}

// ---------------------------------------------------------------------------
// Kernel 1: build combined weight M[o,i] = q*scale + min_val + (U*S)V^T (bf16)
// (unchanged from round 2)
// ---------------------------------------------------------------------------
__global__ __launch_bounds__(256) void build_m(const float* __restrict__ U,
                                               const float* __restrict__ V,
                                               const float* __restrict__ S,
                                               const int* __restrict__ q,
                                               const float* __restrict__ scale_p,
                                               const float* __restrict__ minv_p,
                                               unsigned short* __restrict__ M) {
  __shared__ unsigned short lA[128 * 64];
  __shared__ unsigned short lB[128 * 64];
  const int tid  = threadIdx.x;
  const int wid  = tid >> 6;
  const int lane = tid & 63;
  const int bm = blockIdx.x >> 5;
  const int bn = blockIdx.x & 31;
  const int wm = (wid >> 1) * 64;
  const int wn = (wid & 1) * 64;

  f32x4 acc[4][4] = {};

  const int sr = tid >> 4;
  const int sc = (tid & 15) * 4;

  for (int k0 = 0; k0 < RANK; k0 += 64) {
    __syncthreads();
#pragma unroll
    for (int p = 0; p < 8; ++p) {
      int row = p * 16 + sr;
      f32x4 uv = *(const f32x4*)&U[(size_t)(bm * 128 + row) * RANK + k0 + sc];
      short4v pa;
      pa.x = (short)f2bf(uv.x); pa.y = (short)f2bf(uv.y);
      pa.z = (short)f2bf(uv.z); pa.w = (short)f2bf(uv.w);
      *(short4v*)&lA[row * 64 + sc] = pa;
      f32x4 vv = *(const f32x4*)&V[(size_t)(bn * 128 + row) * RANK + k0 + sc];
      f32x4 sv = *(const f32x4*)&S[k0 + sc];
      short4v pb;
      pb.x = (short)f2bf(vv.x * sv.x); pb.y = (short)f2bf(vv.y * sv.y);
      pb.z = (short)f2bf(vv.z * sv.z); pb.w = (short)f2bf(vv.w * sv.w);
      *(short4v*)&lB[row * 64 + sc] = pb;
    }
    __syncthreads();
#pragma unroll
    for (int kk = 0; kk < 2; ++kk) {
      bf16x8 af[4], bfr[4];
#pragma unroll
      for (int m = 0; m < 4; ++m)
        af[m] = *(const bf16x8*)&lA[(wm + m * 16 + (lane & 15)) * 64 + kk * 32 + (lane >> 4) * 8];
#pragma unroll
      for (int n = 0; n < 4; ++n)
        bfr[n] = *(const bf16x8*)&lB[(wn + n * 16 + (lane & 15)) * 64 + kk * 32 + (lane >> 4) * 8];
#pragma unroll
      for (int m = 0; m < 4; ++m)
#pragma unroll
        for (int n = 0; n < 4; ++n)
          acc[m][n] = __builtin_amdgcn_mfma_f32_16x16x32_bf16(af[m], bfr[n], acc[m][n], 0, 0, 0);
    }
  }

  const float scale = *scale_p;
  const float minv  = *minv_p;
  const int o0 = bm * 128 + wm;
  const int i0 = bn * 128 + wn;
#pragma unroll
  for (int m = 0; m < 4; ++m) {
#pragma unroll
    for (int n = 0; n < 4; ++n) {
      int col = i0 + n * 16 + (lane & 15);
#pragma unroll
      for (int rr = 0; rr < 4; ++rr) {
        int row = o0 + m * 16 + (lane >> 4) * 4 + rr;
        float dq = (float)q[(size_t)row * IN_F + col] * scale + minv;
        M[(size_t)row * IN_F + col] = f2bf(acc[m][n][rr] + dq);
      }
    }
  }
}

// ---------------------------------------------------------------------------
// Kernel 2: main GEMM, 256x256 tile, BK=64, 8 waves, 32x32x16 MFMA,
// FRAGMENT-LINEAR LDS (each 32x32x16 fragment = 1024 contiguous bytes; both
// gload_lds dest and ds_read are base + lane*16 -> zero bank conflicts).
// 2 phases per K-tile (ks01 / ks23), counted vmcnt(8), setprio.
//
// LDS (128 KiB): buf p at p*65536; A frag (ks,mi) at (ks*8+mi)*1024;
//                B at +32768, frag (ks,ni) at (ks*8+ni)*1024.
// Staging: during t.ph1 stage ks23(t+1) into buf q (region last read t-1.ph2);
//          during t.ph2 stage ks01(t+2) into buf p (region last read t.ph1).
// Phase-end vmcnt(8) drains exactly the 4-gload group issued 2 phases ago,
// which is read in the NEXT phase. Tail: vmcnt(4)/vmcnt(0).
// ---------------------------------------------------------------------------
__global__ __launch_bounds__(512, 2) void gemm256(
    const unsigned short* __restrict__ xb,
    const unsigned short* __restrict__ Mw,
    float* __restrict__ out) {
  extern __shared__ __align__(128) char smem[];
  const int tid  = threadIdx.x;
  const int wid  = tid >> 6;
  const int lane = tid & 63;
  const int l31  = lane & 31;
  const int lhi  = lane >> 5;
  const int wqm  = wid >> 2;  // 0..1 : 128-row half
  const int wqn  = wid & 3;   // 0..3 : 64-col slice

  // XCD-aware bijective swizzle (nwg = 512, divisible by 8)
  const int swz = (blockIdx.x & 7) * 64 + (blockIdx.x >> 3);
  const int bm = swz >> 4;   // 0..31 token tiles
  const int bn = swz & 15;   // 0..15 out-feature tiles
  const int row0 = bm * 256;
  const int col0 = bn * 256;

  // Per-thread staging source bases: lane l fetches (row = wid*32 + l31,
  // k = ks*16 + lhi*8 .. +7) of the tile -> lands at frag slot lane*16.
  const unsigned short* aSrc = xb + (size_t)(row0 + wid * 32 + l31) * IN_F + lhi * 8;
  const unsigned short* bSrc = Mw + (size_t)(col0 + wid * 32 + l31) * IN_F + lhi * 8;

  // Stage A/B kshalf h (ks = 2h, 2h+1) of K-tile t into buffer at byte pbuf.
  auto STAGE = [&](int t, int h, unsigned pbuf) {
#pragma unroll
    for (int j = 0; j < 2; ++j) {
      int ks = h * 2 + j;
      gload_lds16(aSrc + t * 64 + ks * 16, smem + pbuf + (ks * 8 + wid) * 1024);
      gload_lds16(bSrc + t * 64 + ks * 16, smem + pbuf + 32768u + (ks * 8 + wid) * 1024);
    }
  };

  // ds_read bases (lane*16 folded in)
  const int aBase = wqm * 4 * 1024 + lane * 16;
  const int bBase = 32768 + wqn * 2 * 1024 + lane * 16;

  f32x16 acc[4][2] = {};  // [mi][ni], 32x32 frags
  bf16x8 a[4][2], b[2][2];

  const int nK = IN_F / 64;  // 64

  // ---- prologue: t0 ks01+ks23 -> buf0; t1 ks01 -> buf1 ----
  STAGE(0, 0, 0u);
  STAGE(0, 1, 0u);
  STAGE(1, 0, 65536u);
  asm volatile("s_waitcnt vmcnt(4)");  // t0 fully landed
  __builtin_amdgcn_sched_barrier(0);
  __builtin_amdgcn_s_barrier();

  for (int t = 0; t < nK; ++t) {
    const unsigned pb = (unsigned)(t & 1) * 65536u;
    const unsigned qb = 65536u - pb;

    // ================= phase 1 : ks 0,1 =================
#pragma unroll
    for (int kk = 0; kk < 2; ++kk) {
#pragma unroll
      for (int mi = 0; mi < 4; ++mi)
        a[mi][kk] = *(const bf16x8*)(smem + pb + kk * 8192 + mi * 1024 + aBase);
#pragma unroll
      for (int ni = 0; ni < 2; ++ni)
        b[ni][kk] = *(const bf16x8*)(smem + pb + kk * 8192 + ni * 1024 + bBase);
    }
    if (t + 1 < nK) STAGE(t + 1, 1, qb);  // ks23 of t+1
    __builtin_amdgcn_s_barrier();
    asm volatile("s_waitcnt lgkmcnt(0)");
    __builtin_amdgcn_sched_barrier(0);
    __builtin_amdgcn_s_setprio(1);
#pragma unroll
    for (int kk = 0; kk < 2; ++kk)
#pragma unroll
      for (int mi = 0; mi < 4; ++mi)
#pragma unroll
        for (int ni = 0; ni < 2; ++ni)
          acc[mi][ni] = __builtin_amdgcn_mfma_f32_32x32x16_bf16(
              a[mi][kk], b[ni][kk], acc[mi][ni], 0, 0, 0);
    __builtin_amdgcn_s_setprio(0);
    __builtin_amdgcn_sched_barrier(0);
    if (t + 1 < nK) asm volatile("s_waitcnt vmcnt(8)");
    else            asm volatile("s_waitcnt vmcnt(0)");
    __builtin_amdgcn_sched_barrier(0);
    __builtin_amdgcn_s_barrier();

    // ================= phase 2 : ks 2,3 =================
#pragma unroll
    for (int kk = 0; kk < 2; ++kk) {
#pragma unroll
      for (int mi = 0; mi < 4; ++mi)
        a[mi][kk] = *(const bf16x8*)(smem + pb + 16384 + kk * 8192 + mi * 1024 + aBase);
#pragma unroll
      for (int ni = 0; ni < 2; ++ni)
        b[ni][kk] = *(const bf16x8*)(smem + pb + 16384 + kk * 8192 + ni * 1024 + bBase);
    }
    if (t + 2 < nK) STAGE(t + 2, 0, pb);  // ks01 of t+2
    __builtin_amdgcn_s_barrier();
    asm volatile("s_waitcnt lgkmcnt(0)");
    __builtin_amdgcn_sched_barrier(0);
    __builtin_amdgcn_s_setprio(1);
#pragma unroll
    for (int kk = 0; kk < 2; ++kk)
#pragma unroll
      for (int mi = 0; mi < 4; ++mi)
#pragma unroll
        for (int ni = 0; ni < 2; ++ni)
          acc[mi][ni] = __builtin_amdgcn_mfma_f32_32x32x16_bf16(
              a[mi][kk], b[ni][kk], acc[mi][ni], 0, 0, 0);
    __builtin_amdgcn_s_setprio(0);
    __builtin_amdgcn_sched_barrier(0);
    if (t + 2 < nK)      asm volatile("s_waitcnt vmcnt(8)");
    else if (t + 1 < nK) asm volatile("s_waitcnt vmcnt(4)");
    __builtin_amdgcn_sched_barrier(0);
    __builtin_amdgcn_s_barrier();
  }

  // ---- epilogue: 32x32 C/D layout: col=lane&31, row=(r&3)+8*(r>>2)+4*lhi ----
#pragma unroll
  for (int mi = 0; mi < 4; ++mi) {
#pragma unroll
    for (int ni = 0; ni < 2; ++ni) {
      int col = col0 + wqn * 64 + ni * 32 + l31;
#pragma unroll
      for (int r = 0; r < 16; ++r) {
        int row = row0 + wqm * 128 + mi * 32 + (r & 3) + 8 * (r >> 2) + 4 * lhi;
        out[(size_t)row * OUT_F + col] = acc[mi][ni][r];
      }
    }
  }
}

// ---------------------------------------------------------------------------
// Fallback main GEMM (128^2, used only if ws < 96 MB): A reg-staged from f32.
// ---------------------------------------------------------------------------
__global__ __launch_bounds__(256) void gemm_main_f(const float* __restrict__ xf,
                                                   const unsigned short* __restrict__ Mw,
                                                   float* __restrict__ out) {
  __shared__ unsigned short lA[128 * 64];
  __shared__ unsigned short lB[128 * 64];
  const int tid  = threadIdx.x;
  const int wid  = tid >> 6;
  const int lane = tid & 63;
  const int nwg = gridDim.x;
  const int cpx = nwg >> 3;
  const int swz = (blockIdx.x & 7) * cpx + (blockIdx.x >> 3);
  const int bm = swz >> 5;
  const int bn = swz & 31;
  const int wm = (wid >> 1) * 64;
  const int wn = (wid & 1) * 64;
  const int row0 = bm * 128;
  const int col0 = bn * 128;

  f32x4 acc[4][4] = {};

  for (int k0 = 0; k0 < IN_F; k0 += 64) {
    __syncthreads();
    const int sr = tid >> 4;
    const int sc = (tid & 15) * 4;
#pragma unroll
    for (int p = 0; p < 8; ++p) {
      int row = p * 16 + sr;
      f32x4 v = *(const f32x4*)&xf[(size_t)(row0 + row) * IN_F + k0 + sc];
      short4v pa;
      pa.x = (short)f2bf(v.x); pa.y = (short)f2bf(v.y);
      pa.z = (short)f2bf(v.z); pa.w = (short)f2bf(v.w);
      *(short4v*)&lA[row * 64 + sc] = pa;
    }
#pragma unroll
    for (int j = 0; j < 4; ++j) {
      int rbase = (wid * 4 + j) * 8;
      const unsigned short* src =
          &Mw[(size_t)(col0 + rbase + (lane >> 3)) * IN_F + k0 + (lane & 7) * 8];
      gload_lds16(src, &lB[rbase * 64]);
    }
    __syncthreads();
#pragma unroll
    for (int kk = 0; kk < 2; ++kk) {
      bf16x8 af[4], bfr[4];
#pragma unroll
      for (int m = 0; m < 4; ++m)
        af[m] = *(const bf16x8*)&lA[(wm + m * 16 + (lane & 15)) * 64 + kk * 32 + (lane >> 4) * 8];
#pragma unroll
      for (int n = 0; n < 4; ++n)
        bfr[n] = *(const bf16x8*)&lB[(wn + n * 16 + (lane & 15)) * 64 + kk * 32 + (lane >> 4) * 8];
#pragma unroll
      for (int m = 0; m < 4; ++m)
#pragma unroll
        for (int n = 0; n < 4; ++n)
          acc[m][n] = __builtin_amdgcn_mfma_f32_16x16x32_bf16(af[m], bfr[n], acc[m][n], 0, 0, 0);
    }
  }

#pragma unroll
  for (int m = 0; m < 4; ++m) {
#pragma unroll
    for (int n = 0; n < 4; ++n) {
      int col = col0 + wn + n * 16 + (lane & 15);
#pragma unroll
      for (int rr = 0; rr < 4; ++rr) {
        int row = row0 + wm + m * 16 + (lane >> 4) * 4 + rr;
        out[(size_t)row * OUT_F + col] = acc[m][n][rr];
      }
    }
  }
}

// ---------------------------------------------------------------------------
extern "C" void kernel_launch(void* const* d_in, const int* in_sizes, int n_in,
                              void* d_out, int out_size, void* d_ws, size_t ws_size,
                              hipStream_t stream) {
  const float* x      = (const float*)d_in[0];
  const int*   q      = (const int*)d_in[1];
  const float* scale  = (const float*)d_in[2];
  const float* minv   = (const float*)d_in[3];
  const float* U      = (const float*)d_in[4];
  const float* S      = (const float*)d_in[5];
  const float* V      = (const float*)d_in[6];
  float* out = (float*)d_out;

  const size_t xb_bytes = (size_t)TOKENS * IN_F * 2;  // 64 MB
  const size_t m_bytes  = (size_t)OUT_F * IN_F * 2;   // 32 MB

  if (ws_size >= xb_bytes + m_bytes) {
    unsigned short* xbuf = (unsigned short*)d_ws;
    unsigned short* Mw   = (unsigned short*)((char*)d_ws + xb_bytes);
    (void)hipFuncSetAttribute((const void*)gemm256,
                              hipFuncAttributeMaxDynamicSharedMemorySize,
                              131072);
    build_m<<<dim3(1024), dim3(256), 0, stream>>>(U, V, S, q, scale, minv, Mw);
    convert_x<<<dim3(2048), dim3(256), 0, stream>>>(x, xbuf, TOKENS * IN_F / 4);
    gemm256<<<dim3(512), dim3(512), 131072, stream>>>(xbuf, Mw, out);
  } else {
    unsigned short* Mw = (unsigned short*)d_ws;  // needs 32 MB
    build_m<<<dim3(1024), dim3(256), 0, stream>>>(U, V, S, q, scale, minv, Mw);
    gemm_main_f<<<dim3(2048), dim3(256), 0, stream>>>(x, Mw, out);
  }
}

// Round 4
// 332.570 us; speedup vs baseline: 1.2531x; 1.2531x over previous
//
#include <hip/hip_runtime.h>
#include <hip/hip_bf16.h>
#include <stdint.h>

#define TOKENS 8192
#define IN_F   4096
#define OUT_F  4096
#define RANK   512

typedef __attribute__((ext_vector_type(8))) __bf16 bf16x8;
typedef __attribute__((ext_vector_type(4))) float f32x4;
typedef __attribute__((ext_vector_type(4))) short short4v;

static __device__ __forceinline__ unsigned short f2bf(float f) {
  union { float f; unsigned u; } v; v.f = f;
  return (unsigned short)((v.u + 0x7FFFu + ((v.u >> 16) & 1u)) >> 16);
}

static __device__ __forceinline__ void gload_lds16(const void* g, void* l) {
  __builtin_amdgcn_global_load_lds(
      (const __attribute__((address_space(1))) unsigned*)g,
      (__attribute__((address_space(3))) unsigned*)l, 16, 0, 0);
}

// ---------------------------------------------------------------------------
// Kernel 0 (fused prep): blocks [0,512) convert x f32->bf16;
// blocks [512,1536) build combined weight
//   M[o,i] = q[o,i]*scale + min_val + sum_r U[o,r]*S[r]*V[i,r]   (bf16)
// Both are memory-bound; fusing overlaps their HBM streams.
// ---------------------------------------------------------------------------
__global__ __launch_bounds__(256) void prep_fused(
    const float* __restrict__ x, unsigned short* __restrict__ xb,
    const float* __restrict__ U, const float* __restrict__ V,
    const float* __restrict__ S, const int* __restrict__ q,
    const float* __restrict__ scale_p, const float* __restrict__ minv_p,
    unsigned short* __restrict__ M) {
  __shared__ unsigned short lA[128 * 64];
  __shared__ unsigned short lB[128 * 64];

  if (blockIdx.x < 512) {
    // ---- convert_x path ----
    const int n4 = TOKENS * IN_F / 4;
    int idx = blockIdx.x * 256 + threadIdx.x;
    const int stride = 512 * 256;
    for (int i = idx; i < n4; i += stride) {
      f32x4 v = ((const f32x4*)x)[i];
      short4v o;
      o.x = (short)f2bf(v.x);
      o.y = (short)f2bf(v.y);
      o.z = (short)f2bf(v.z);
      o.w = (short)f2bf(v.w);
      ((short4v*)xb)[i] = o;
    }
    return;
  }

  // ---- build_m path ----
  const int bid  = blockIdx.x - 512;  // 0..1023
  const int tid  = threadIdx.x;
  const int wid  = tid >> 6;
  const int lane = tid & 63;
  const int bm = bid >> 5;
  const int bn = bid & 31;
  const int wm = (wid >> 1) * 64;
  const int wn = (wid & 1) * 64;

  f32x4 acc[4][4] = {};

  const int sr = tid >> 4;
  const int sc = (tid & 15) * 4;

  for (int k0 = 0; k0 < RANK; k0 += 64) {
    __syncthreads();
#pragma unroll
    for (int p = 0; p < 8; ++p) {
      int row = p * 16 + sr;
      f32x4 uv = *(const f32x4*)&U[(size_t)(bm * 128 + row) * RANK + k0 + sc];
      short4v pa;
      pa.x = (short)f2bf(uv.x); pa.y = (short)f2bf(uv.y);
      pa.z = (short)f2bf(uv.z); pa.w = (short)f2bf(uv.w);
      *(short4v*)&lA[row * 64 + sc] = pa;
      f32x4 vv = *(const f32x4*)&V[(size_t)(bn * 128 + row) * RANK + k0 + sc];
      f32x4 sv = *(const f32x4*)&S[k0 + sc];
      short4v pb;
      pb.x = (short)f2bf(vv.x * sv.x); pb.y = (short)f2bf(vv.y * sv.y);
      pb.z = (short)f2bf(vv.z * sv.z); pb.w = (short)f2bf(vv.w * sv.w);
      *(short4v*)&lB[row * 64 + sc] = pb;
    }
    __syncthreads();
#pragma unroll
    for (int kk = 0; kk < 2; ++kk) {
      bf16x8 af[4], bfr[4];
#pragma unroll
      for (int m = 0; m < 4; ++m)
        af[m] = *(const bf16x8*)&lA[(wm + m * 16 + (lane & 15)) * 64 + kk * 32 + (lane >> 4) * 8];
#pragma unroll
      for (int n = 0; n < 4; ++n)
        bfr[n] = *(const bf16x8*)&lB[(wn + n * 16 + (lane & 15)) * 64 + kk * 32 + (lane >> 4) * 8];
#pragma unroll
      for (int m = 0; m < 4; ++m)
#pragma unroll
        for (int n = 0; n < 4; ++n)
          acc[m][n] = __builtin_amdgcn_mfma_f32_16x16x32_bf16(af[m], bfr[n], acc[m][n], 0, 0, 0);
    }
  }

  const float scale = *scale_p;
  const float minv  = *minv_p;
  const int o0 = bm * 128 + wm;
  const int i0 = bn * 128 + wn;
#pragma unroll
  for (int m = 0; m < 4; ++m) {
#pragma unroll
    for (int n = 0; n < 4; ++n) {
      int col = i0 + n * 16 + (lane & 15);
#pragma unroll
      for (int rr = 0; rr < 4; ++rr) {
        int row = o0 + m * 16 + (lane >> 4) * 4 + rr;
        float dq = (float)q[(size_t)row * IN_F + col] * scale + minv;
        M[(size_t)row * IN_F + col] = f2bf(acc[m][n][rr] + dq);
      }
    }
  }
}

// ---------------------------------------------------------------------------
// Kernel 2: main GEMM, 256x256 tile, BK=64, 8 waves, 8-phase (4 phases/K-tile,
// 2-tile buffer parity), counted vmcnt(6), st-swizzled LDS, setprio.
// (round-2 kernel; deltas: kk-outer MFMA order, lgkmcnt(8) hint in ph1)
//   out[t,o] = sum_i xb[t,i] * Mw[o,i]
// LDS (dynamic, 128 KiB): buf p at p*65536; A[256][64]bf16 at +0 (half h at
// +h*16384), B[256][64] at +32768. Element (r,cbyte) at byte
// r*128 + (cbyte ^ ((r&7)<<4)); staging keeps LDS linear and pre-swizzles the
// per-lane GLOBAL source column (both-sides involution).
// Quadrant order per K-tile: ph1=(0,0) ph2=(0,1) ph3=(1,1) ph4=(1,0).
// Staging during tile t: ph1 -> t+1.A1 (other buf); ph2 -> t+2.A0; ph3 ->
// t+2.B0; ph4 -> t+2.B1. vmcnt(6) at ph4 leaves exactly t+2's 3 half-tiles in
// flight; everything of tile t+1 is landed before its ph1 ds_reads.
// ---------------------------------------------------------------------------
__global__ __launch_bounds__(512, 2) void gemm256(
    const unsigned short* __restrict__ xb,
    const unsigned short* __restrict__ Mw,
    float* __restrict__ out) {
  extern __shared__ __align__(128) char smem[];
  const int tid  = threadIdx.x;
  const int wid  = tid >> 6;
  const int lane = tid & 63;
  const int wqm  = wid >> 2;  // 0..1 : 64-row slice within a 128x128 quadrant
  const int wqn  = wid & 3;   // 0..3 : 32-col slice

  // XCD-aware bijective swizzle (nwg = 512, divisible by 8)
  const int swz = (blockIdx.x & 7) * 64 + (blockIdx.x >> 3);
  const int bm = swz >> 4;   // 0..31 token tiles
  const int bn = swz & 15;   // 0..15 out-feature tiles
  const int row0 = bm * 256;
  const int col0 = bn * 256;

  // Per-lane ds_read byte offsets within an A/B tile (swizzle folded in).
  int offA[4][2], offB[2][2];
#pragma unroll
  for (int m = 0; m < 4; ++m)
#pragma unroll
    for (int kk = 0; kk < 2; ++kk) {
      int r = wqm * 64 + m * 16 + (lane & 15);
      int cb = kk * 64 + (lane >> 4) * 16;
      offA[m][kk] = r * 128 + (cb ^ ((r & 7) << 4));
    }
#pragma unroll
  for (int n = 0; n < 2; ++n)
#pragma unroll
    for (int kk = 0; kk < 2; ++kk) {
      int r = wqn * 32 + n * 16 + (lane & 15);
      int cb = kk * 64 + (lane >> 4) * 16;
      offB[n][kk] = r * 128 + (cb ^ ((r & 7) << 4));
    }

  // Pre-swizzled global source column (elements) for staging.
  const int sco = (((lane & 7) ^ (lane >> 3)) << 3);
  const int srw = lane >> 3;

  // Stage one 128x64 bf16 half-tile: src rows [g0,g0+128), k cols [k0,k0+64)
  // into LDS bytes [lb, lb+16384), linear dest (wave-uniform base + lane*16).
  auto STAGE = [&](const unsigned short* __restrict__ src, int g0, int k0,
                   unsigned lb) {
#pragma unroll
    for (int j = 0; j < 2; ++j) {
      int r = (wid * 2 + j) * 8;
      const unsigned short* g =
          src + (size_t)(g0 + r + srw) * IN_F + k0 + sco;
      gload_lds16(g, smem + lb + r * 128);
    }
  };

  f32x4 acc[4][4][2] = {};  // [quadrant][m][n]

  // ---- prologue: tile0 all 4 halves -> buf0; tile1 A0,B0,B1 -> buf1 ----
  STAGE(xb, row0,       0, 0u);          // t0 A0
  STAGE(Mw, col0,       0, 32768u);      // t0 B0
  STAGE(Mw, col0 + 128, 0, 49152u);      // t0 B1
  STAGE(xb, row0 + 128, 0, 16384u);      // t0 A1
  STAGE(xb, row0,       64, 65536u);     // t1 A0
  STAGE(Mw, col0,       64, 98304u);     // t1 B0
  STAGE(Mw, col0 + 128, 64, 114688u);    // t1 B1
  asm volatile("s_waitcnt vmcnt(6)");    // tile0 landed; t1 A0/B0/B1 in flight
  __builtin_amdgcn_sched_barrier(0);
  __builtin_amdgcn_s_barrier();

  const int nK = IN_F / 64;  // 64
  bf16x8 a[4][2], b0[2][2], b1[2][2];

  for (int t = 0; t < nK; ++t) {
    const unsigned pb = (unsigned)(t & 1) * 65536u;
    const unsigned qb = 65536u - pb;
    const int k1 = (t + 1) * 64;
    const int k2 = (t + 2) * 64;

    // ================= phase 1 : Q(0,0) =================
#pragma unroll
    for (int m = 0; m < 4; ++m)
#pragma unroll
      for (int kk = 0; kk < 2; ++kk)
        a[m][kk] = *(const bf16x8*)(smem + pb + offA[m][kk]);
#pragma unroll
    for (int n = 0; n < 2; ++n)
#pragma unroll
      for (int kk = 0; kk < 2; ++kk)
        b0[n][kk] = *(const bf16x8*)(smem + pb + 32768u + offB[n][kk]);
    if (t + 1 < nK) STAGE(xb, row0 + 128, k1, qb + 16384u);  // t+1 A1
    asm volatile("s_waitcnt lgkmcnt(8)");  // early drain (12 ds_reads issued)
    __builtin_amdgcn_s_barrier();
    asm volatile("s_waitcnt lgkmcnt(0)");
    __builtin_amdgcn_sched_barrier(0);
    __builtin_amdgcn_s_setprio(1);
#pragma unroll
    for (int kk = 0; kk < 2; ++kk)
#pragma unroll
      for (int m = 0; m < 4; ++m)
#pragma unroll
        for (int n = 0; n < 2; ++n)
          acc[0][m][n] = __builtin_amdgcn_mfma_f32_16x16x32_bf16(
              a[m][kk], b0[n][kk], acc[0][m][n], 0, 0, 0);
    __builtin_amdgcn_s_setprio(0);
    __builtin_amdgcn_sched_barrier(0);
    __builtin_amdgcn_s_barrier();

    // ================= phase 2 : Q(0,1) =================
#pragma unroll
    for (int n = 0; n < 2; ++n)
#pragma unroll
      for (int kk = 0; kk < 2; ++kk)
        b1[n][kk] = *(const bf16x8*)(smem + pb + 49152u + offB[n][kk]);
    if (t + 2 < nK) STAGE(xb, row0, k2, pb);  // t+2 A0
    __builtin_amdgcn_s_barrier();
    asm volatile("s_waitcnt lgkmcnt(0)");
    __builtin_amdgcn_sched_barrier(0);
    __builtin_amdgcn_s_setprio(1);
#pragma unroll
    for (int kk = 0; kk < 2; ++kk)
#pragma unroll
      for (int m = 0; m < 4; ++m)
#pragma unroll
        for (int n = 0; n < 2; ++n)
          acc[1][m][n] = __builtin_amdgcn_mfma_f32_16x16x32_bf16(
              a[m][kk], b1[n][kk], acc[1][m][n], 0, 0, 0);
    __builtin_amdgcn_s_setprio(0);
    __builtin_amdgcn_sched_barrier(0);
    __builtin_amdgcn_s_barrier();

    // ================= phase 3 : Q(1,1) =================
#pragma unroll
    for (int m = 0; m < 4; ++m)
#pragma unroll
      for (int kk = 0; kk < 2; ++kk)
        a[m][kk] = *(const bf16x8*)(smem + pb + 16384u + offA[m][kk]);
    if (t + 2 < nK) STAGE(Mw, col0, k2, pb + 32768u);  // t+2 B0
    __builtin_amdgcn_s_barrier();
    asm volatile("s_waitcnt lgkmcnt(0)");
    __builtin_amdgcn_sched_barrier(0);
    __builtin_amdgcn_s_setprio(1);
#pragma unroll
    for (int kk = 0; kk < 2; ++kk)
#pragma unroll
      for (int m = 0; m < 4; ++m)
#pragma unroll
        for (int n = 0; n < 2; ++n)
          acc[2][m][n] = __builtin_amdgcn_mfma_f32_16x16x32_bf16(
              a[m][kk], b1[n][kk], acc[2][m][n], 0, 0, 0);
    __builtin_amdgcn_s_setprio(0);
    __builtin_amdgcn_sched_barrier(0);
    __builtin_amdgcn_s_barrier();

    // ================= phase 4 : Q(1,0) =================
    if (t + 2 < nK) {
      STAGE(Mw, col0 + 128, k2, pb + 49152u);  // t+2 B1
      asm volatile("s_waitcnt vmcnt(6)");      // tile t+1 fully landed
    } else if (t + 1 < nK) {
      asm volatile("s_waitcnt vmcnt(0)");      // epilogue drain
    }
    __builtin_amdgcn_sched_barrier(0);
    __builtin_amdgcn_s_barrier();
    __builtin_amdgcn_s_setprio(1);
#pragma unroll
    for (int kk = 0; kk < 2; ++kk)
#pragma unroll
      for (int m = 0; m < 4; ++m)
#pragma unroll
        for (int n = 0; n < 2; ++n)
          acc[3][m][n] = __builtin_amdgcn_mfma_f32_16x16x32_bf16(
              a[m][kk], b0[n][kk], acc[3][m][n], 0, 0, 0);
    __builtin_amdgcn_s_setprio(0);
    __builtin_amdgcn_sched_barrier(0);
    __builtin_amdgcn_s_barrier();
  }

  // ---- epilogue ----
  const int qm_[4] = {0, 0, 1, 1};
  const int qn_[4] = {0, 1, 1, 0};
#pragma unroll
  for (int q = 0; q < 4; ++q) {
#pragma unroll
    for (int m = 0; m < 4; ++m) {
#pragma unroll
      for (int n = 0; n < 2; ++n) {
        int col = col0 + qn_[q] * 128 + wqn * 32 + n * 16 + (lane & 15);
#pragma unroll
        for (int rr = 0; rr < 4; ++rr) {
          int row = row0 + qm_[q] * 128 + wqm * 64 + m * 16 + (lane >> 4) * 4 + rr;
          out[(size_t)row * OUT_F + col] = acc[q][m][n][rr];
        }
      }
    }
  }
}

// ---------------------------------------------------------------------------
// Fallback main GEMM (128^2, used only if ws < 96 MB): A reg-staged from f32.
// ---------------------------------------------------------------------------
__global__ __launch_bounds__(256) void gemm_main_f(const float* __restrict__ xf,
                                                   const unsigned short* __restrict__ Mw,
                                                   float* __restrict__ out) {
  __shared__ unsigned short lA[128 * 64];
  __shared__ unsigned short lB[128 * 64];
  const int tid  = threadIdx.x;
  const int wid  = tid >> 6;
  const int lane = tid & 63;
  const int nwg = gridDim.x;
  const int cpx = nwg >> 3;
  const int swz = (blockIdx.x & 7) * cpx + (blockIdx.x >> 3);
  const int bm = swz >> 5;
  const int bn = swz & 31;
  const int wm = (wid >> 1) * 64;
  const int wn = (wid & 1) * 64;
  const int row0 = bm * 128;
  const int col0 = bn * 128;

  f32x4 acc[4][4] = {};

  for (int k0 = 0; k0 < IN_F; k0 += 64) {
    __syncthreads();
    const int sr = tid >> 4;
    const int sc = (tid & 15) * 4;
#pragma unroll
    for (int p = 0; p < 8; ++p) {
      int row = p * 16 + sr;
      f32x4 v = *(const f32x4*)&xf[(size_t)(row0 + row) * IN_F + k0 + sc];
      short4v pa;
      pa.x = (short)f2bf(v.x); pa.y = (short)f2bf(v.y);
      pa.z = (short)f2bf(v.z); pa.w = (short)f2bf(v.w);
      *(short4v*)&lA[row * 64 + sc] = pa;
    }
#pragma unroll
    for (int j = 0; j < 4; ++j) {
      int rbase = (wid * 4 + j) * 8;
      const unsigned short* src =
          &Mw[(size_t)(col0 + rbase + (lane >> 3)) * IN_F + k0 + (lane & 7) * 8];
      gload_lds16(src, &lB[rbase * 64]);
    }
    __syncthreads();
#pragma unroll
    for (int kk = 0; kk < 2; ++kk) {
      bf16x8 af[4], bfr[4];
#pragma unroll
      for (int m = 0; m < 4; ++m)
        af[m] = *(const bf16x8*)&lA[(wm + m * 16 + (lane & 15)) * 64 + kk * 32 + (lane >> 4) * 8];
#pragma unroll
      for (int n = 0; n < 4; ++n)
        bfr[n] = *(const bf16x8*)&lB[(wn + n * 16 + (lane & 15)) * 64 + kk * 32 + (lane >> 4) * 8];
#pragma unroll
      for (int m = 0; m < 4; ++m)
#pragma unroll
        for (int n = 0; n < 4; ++n)
          acc[m][n] = __builtin_amdgcn_mfma_f32_16x16x32_bf16(af[m], bfr[n], acc[m][n], 0, 0, 0);
    }
  }

#pragma unroll
  for (int m = 0; m < 4; ++m) {
#pragma unroll
    for (int n = 0; n < 4; ++n) {
      int col = col0 + wn + n * 16 + (lane & 15);
#pragma unroll
      for (int rr = 0; rr < 4; ++rr) {
        int row = row0 + wm + m * 16 + (lane >> 4) * 4 + rr;
        out[(size_t)row * OUT_F + col] = acc[m][n][rr];
      }
    }
  }
}

// ---------------------------------------------------------------------------
extern "C" void kernel_launch(void* const* d_in, const int* in_sizes, int n_in,
                              void* d_out, int out_size, void* d_ws, size_t ws_size,
                              hipStream_t stream) {
  const float* x      = (const float*)d_in[0];
  const int*   q      = (const int*)d_in[1];
  const float* scale  = (const float*)d_in[2];
  const float* minv   = (const float*)d_in[3];
  const float* U      = (const float*)d_in[4];
  const float* S      = (const float*)d_in[5];
  const float* V      = (const float*)d_in[6];
  float* out = (float*)d_out;

  const size_t xb_bytes = (size_t)TOKENS * IN_F * 2;  // 64 MB
  const size_t m_bytes  = (size_t)OUT_F * IN_F * 2;   // 32 MB

  if (ws_size >= xb_bytes + m_bytes) {
    unsigned short* xbuf = (unsigned short*)d_ws;
    unsigned short* Mw   = (unsigned short*)((char*)d_ws + xb_bytes);
    (void)hipFuncSetAttribute((const void*)gemm256,
                              hipFuncAttributeMaxDynamicSharedMemorySize,
                              131072);
    prep_fused<<<dim3(1536), dim3(256), 0, stream>>>(x, xbuf, U, V, S, q,
                                                     scale, minv, Mw);
    gemm256<<<dim3(512), dim3(512), 131072, stream>>>(xbuf, Mw, out);
  } else {
    unsigned short* Mw = (unsigned short*)d_ws;  // needs 32 MB
    prep_fused<<<dim3(1536), dim3(256), 0, stream>>>(nullptr, nullptr, U, V, S,
                                                     q, scale, minv, Mw);
    gemm_main_f<<<dim3(2048), dim3(256), 0, stream>>>(x, Mw, out);
  }
}